// Round 1
// baseline (565.830 us; speedup 1.0000x reference)
//
#include <hip/hip_runtime.h>
#include <hip/hip_bf16.h>
#include <stdint.h>

// ---------------------------------------------------------------------------
// QuantizedLinear: y = x @ (qweight * scale)^T + bias
//   x:       [M=8192, K=4096] fp32
//   qweight: [N=4096, K=4096] int32 in [0,127)  -> exact in bf16
//   scale:   [1] fp32
//   bias:    [N] fp32
//   out:     [M, N] fp32
// Strategy: convert x and qweight to bf16 in d_ws, then m97-structure
// 128x128-tile bf16 MFMA GEMM (B^T layout) with fused scale+bias epilogue.
// ---------------------------------------------------------------------------

#define M_ 8192
#define N_ 4096
#define K_ 4096

typedef __bf16 bf16x8 __attribute__((ext_vector_type(8)));
typedef float  f32x4  __attribute__((ext_vector_type(4)));

typedef __attribute__((address_space(1))) void gvoid_t;
typedef __attribute__((address_space(3))) void lvoid_t;

// async global->LDS, 16B per lane. LDS dest must be wave-uniform base + lane*16.
__device__ __forceinline__ void gload_lds16(const void* g, void* l) {
    __builtin_amdgcn_global_load_lds(
        (gvoid_t*)(uintptr_t)g,
        (lvoid_t*)(uint32_t)(uintptr_t)l,
        16, 0, 0);
}

// --------------------------- conversion kernels ----------------------------

__global__ __launch_bounds__(256) void k_cvt_x(const float* __restrict__ x,
                                               __bf16* __restrict__ o, int n8) {
    int i = blockIdx.x * 256 + threadIdx.x;
    if (i >= n8) return;
    const float4* xv = (const float4*)x;
    float4 a = xv[i * 2];
    float4 b = xv[i * 2 + 1];
    bf16x8 r;
    r[0] = (__bf16)a.x; r[1] = (__bf16)a.y; r[2] = (__bf16)a.z; r[3] = (__bf16)a.w;
    r[4] = (__bf16)b.x; r[5] = (__bf16)b.y; r[6] = (__bf16)b.z; r[7] = (__bf16)b.w;
    ((bf16x8*)o)[i] = r;
}

__global__ __launch_bounds__(256) void k_cvt_w(const int* __restrict__ q,
                                               __bf16* __restrict__ o, int n8) {
    int i = blockIdx.x * 256 + threadIdx.x;
    if (i >= n8) return;
    const int4* qv = (const int4*)q;
    int4 a = qv[i * 2];
    int4 b = qv[i * 2 + 1];
    bf16x8 r;
    r[0] = (__bf16)(float)a.x; r[1] = (__bf16)(float)a.y;
    r[2] = (__bf16)(float)a.z; r[3] = (__bf16)(float)a.w;
    r[4] = (__bf16)(float)b.x; r[5] = (__bf16)(float)b.y;
    r[6] = (__bf16)(float)b.z; r[7] = (__bf16)(float)b.w;
    ((bf16x8*)o)[i] = r;
}

// ------------------------------- GEMM kernel -------------------------------
// A: [M,K] bf16 row-major; B: [N,K] bf16 row-major (i.e. B^T of the math GEMM)
// C: [M,N] fp32.  Tile 128x128, BK=32, 4 waves (each owns a 64x64 quadrant,
// 4x4 grid of 16x16x32 MFMA fragments).

__global__ __launch_bounds__(256) void k_gemm(const __bf16* __restrict__ A,
                                              const __bf16* __restrict__ B,
                                              const float* __restrict__ scale,
                                              const float* __restrict__ bias,
                                              float* __restrict__ C) {
    __shared__ __bf16 As[128 * 32];
    __shared__ __bf16 Bs[128 * 32];

    const int tid  = threadIdx.x;
    const int lane = tid & 63;
    const int wave = tid >> 6;
    const int wr = wave >> 1;          // wave row quadrant (0..1)
    const int wc = wave & 1;           // wave col quadrant (0..1)
    const int row0 = blockIdx.y * 128; // M offset
    const int col0 = blockIdx.x * 128; // N offset

    f32x4 acc[4][4];
#pragma unroll
    for (int m = 0; m < 4; ++m)
#pragma unroll
        for (int n = 0; n < 4; ++n) acc[m][n] = (f32x4){0.f, 0.f, 0.f, 0.f};

    // staging: 128 rows x 32 cols bf16 = 512 chunks of 16B per tile.
    // chunk f: row = f>>2, col = (f&3)*8. Thread t stages f=t and f=t+256.
    // LDS offset = f*16 bytes -> per wave: base + lane*16 (linear). OK for
    // global_load_lds (wave-uniform base + lane*size).
    const int f0 = tid, f1 = tid + 256;
    const int ra0 = f0 >> 2, ca0 = (f0 & 3) * 8;
    const int ra1 = f1 >> 2, ca1 = (f1 & 3) * 8;
    const __bf16* Abase = A + (size_t)row0 * K_;
    const __bf16* Bbase = B + (size_t)col0 * K_;

    // MFMA fragment addressing (16x16x32 bf16):
    //   A: lane holds row = lane&15, k = (lane>>4)*8 + j  (8 contiguous bf16)
    //   B: lane holds col = lane&15, k = (lane>>4)*8 + j
    const int lr = lane & 15;
    const int lk = (lane >> 4) * 8;

    for (int k0 = 0; k0 < K_; k0 += 32) {
        gload_lds16(Abase + (size_t)ra0 * K_ + k0 + ca0, &As[f0 * 8]);
        gload_lds16(Abase + (size_t)ra1 * K_ + k0 + ca1, &As[f1 * 8]);
        gload_lds16(Bbase + (size_t)ra0 * K_ + k0 + ca0, &Bs[f0 * 8]);
        gload_lds16(Bbase + (size_t)ra1 * K_ + k0 + ca1, &Bs[f1 * 8]);
        __syncthreads();   // drains vmcnt(0): staged data visible

        bf16x8 af[4], bfr[4];
#pragma unroll
        for (int m = 0; m < 4; ++m)
            af[m] = *(const bf16x8*)&As[(wr * 64 + m * 16 + lr) * 32 + lk];
#pragma unroll
        for (int n = 0; n < 4; ++n)
            bfr[n] = *(const bf16x8*)&Bs[(wc * 64 + n * 16 + lr) * 32 + lk];

#pragma unroll
        for (int m = 0; m < 4; ++m)
#pragma unroll
            for (int n = 0; n < 4; ++n)
                acc[m][n] = __builtin_amdgcn_mfma_f32_16x16x32_bf16(
                    af[m], bfr[n], acc[m][n], 0, 0, 0);

        __syncthreads();   // all waves done reading before next overwrite
    }

    // epilogue: C/D layout (m89-verified): col = lane&15, row = (lane>>4)*4 + j
    const float s = scale[0];
    const int rq = (lane >> 4) * 4;
#pragma unroll
    for (int n = 0; n < 4; ++n) {
        const int gc = col0 + wc * 64 + n * 16 + lr;
        const float bv = bias[gc];
#pragma unroll
        for (int m = 0; m < 4; ++m) {
            const int gr = row0 + wr * 64 + m * 16 + rq;
#pragma unroll
            for (int j = 0; j < 4; ++j)
                C[(size_t)(gr + j) * N_ + gc] = acc[m][n][j] * s + bv;
        }
    }
}

// ------------------------------- launcher ----------------------------------

extern "C" void kernel_launch(void* const* d_in, const int* in_sizes, int n_in,
                              void* d_out, int out_size, void* d_ws, size_t ws_size,
                              hipStream_t stream) {
    const float* x     = (const float*)d_in[0];
    const int*   qw    = (const int*)d_in[1];
    const float* scale = (const float*)d_in[2];
    const float* bias  = (const float*)d_in[3];
    float*       out   = (float*)d_out;

    __bf16* xb = (__bf16*)d_ws;
    __bf16* wb = (__bf16*)((char*)d_ws + (size_t)M_ * K_ * sizeof(__bf16));

    const int n8x = M_ * K_ / 8;   // 4,194,304
    const int n8w = N_ * K_ / 8;   // 2,097,152
    k_cvt_x<<<(n8x + 255) / 256, 256, 0, stream>>>(x, xb, n8x);
    k_cvt_w<<<(n8w + 255) / 256, 256, 0, stream>>>(qw, wb, n8w);

    dim3 grid(N_ / 128, M_ / 128);   // (32, 64)
    k_gemm<<<grid, 256, 0, stream>>>(xb, wb, scale, bias, out);
}

// Round 2
// 490.465 us; speedup vs baseline: 1.1537x; 1.1537x over previous
//
#include <hip/hip_runtime.h>
#include <hip/hip_bf16.h>
#include <stdint.h>

// ---------------------------------------------------------------------------
// QuantizedLinear: y = x @ (qweight * scale)^T + bias
//   x [8192,4096] f32, qweight [4096,4096] i32 (exact in bf16), out f32.
// bf16 MFMA GEMM, 256x256 tile, BK=64, 8 waves, 4-phase/K-tile schedule with
// counted vmcnt (T3+T4), XOR bank swizzle (T2), setprio (T5).
// ---------------------------------------------------------------------------

#define M_ 8192
#define N_ 4096
#define K_ 4096
#define NT   (K_ / 64)     // 64 K-tiles
#define NTm1 (NT - 1)

typedef __bf16 bf16x8 __attribute__((ext_vector_type(8)));
typedef float  f32x4  __attribute__((ext_vector_type(4)));

typedef __attribute__((address_space(1))) void gvoid_t;
typedef __attribute__((address_space(3))) void lvoid_t;

__device__ __forceinline__ void gload_lds16(const __bf16* g, __bf16* l) {
    __builtin_amdgcn_global_load_lds(
        (gvoid_t*)(uintptr_t)g,
        (lvoid_t*)(uint32_t)(uintptr_t)l, 16, 0, 0);
}

#define BAR()  asm volatile("s_barrier" ::: "memory")

// --------------------------- conversion kernels ----------------------------

__global__ __launch_bounds__(256) void k_cvt_x(const float* __restrict__ x,
                                               __bf16* __restrict__ o, int n8) {
    const int stride = gridDim.x * 256;
    for (int i = blockIdx.x * 256 + threadIdx.x; i < n8; i += stride) {
        float4 a = ((const float4*)x)[(size_t)i * 2];
        float4 b = ((const float4*)x)[(size_t)i * 2 + 1];
        bf16x8 r;
        r[0] = (__bf16)a.x; r[1] = (__bf16)a.y; r[2] = (__bf16)a.z; r[3] = (__bf16)a.w;
        r[4] = (__bf16)b.x; r[5] = (__bf16)b.y; r[6] = (__bf16)b.z; r[7] = (__bf16)b.w;
        ((bf16x8*)o)[i] = r;
    }
}

__global__ __launch_bounds__(256) void k_cvt_w(const int* __restrict__ q,
                                               __bf16* __restrict__ o, int n8) {
    const int stride = gridDim.x * 256;
    for (int i = blockIdx.x * 256 + threadIdx.x; i < n8; i += stride) {
        int4 a = ((const int4*)q)[(size_t)i * 2];
        int4 b = ((const int4*)q)[(size_t)i * 2 + 1];
        bf16x8 r;
        r[0] = (__bf16)(float)a.x; r[1] = (__bf16)(float)a.y;
        r[2] = (__bf16)(float)a.z; r[3] = (__bf16)(float)a.w;
        r[4] = (__bf16)(float)b.x; r[5] = (__bf16)(float)b.y;
        r[6] = (__bf16)(float)b.z; r[7] = (__bf16)(float)b.w;
        ((bf16x8*)o)[i] = r;
    }
}

// ------------------------------- GEMM kernel -------------------------------
// LDS regions (bf16 elements): A(d,h) at (d*2+h)*8192 ; B(d,h) at 32768 + same.
// Half-tile = 128 rows x 64 k (16 KiB). Swizzle: 16B-slot s stored at s^(row&7).

__global__ __launch_bounds__(512, 2)
void k_gemm(const __bf16* __restrict__ A, const __bf16* __restrict__ B,
            const float* __restrict__ scale, const float* __restrict__ bias,
            float* __restrict__ C) {
    __shared__ __bf16 sm[65536];   // 128 KiB

    const int tid  = threadIdx.x;
    const int lane = tid & 63;
    const int wave = tid >> 6;
    const int wr   = wave >> 2;       // 0..1
    const int wc   = wave & 3;        // 0..3
    const int lr   = lane & 15;
    const int lg   = lane >> 4;       // 0..3
    const int row0 = blockIdx.y * 256;
    const int col0 = blockIdx.x * 256;

    __bf16* smA = sm;
    __bf16* smB = sm + 32768;

    f32x4 acc[8][4];
#pragma unroll
    for (int m = 0; m < 8; ++m)
#pragma unroll
        for (int n = 0; n < 4; ++n) acc[m][n] = (f32x4){0.f, 0.f, 0.f, 0.f};

    // staging: chunk q (0..1023) of a half-tile -> LDS elem q*8 (linear).
    // logical (row=q>>3, slot=q&7); global data block = slot ^ (row&7).
    const int q0 = tid, q1 = tid + 512;
    const int r0 = q0 >> 3, s0 = q0 & 7;
    const int r1 = q1 >> 3, s1 = q1 & 7;
    const int c0 = (s0 ^ (r0 & 7)) * 8;
    const int c1 = (s1 ^ (r1 & 7)) * 8;
    const __bf16* a00 = A + (size_t)(row0 +       r0) * K_ + c0;
    const __bf16* a01 = A + (size_t)(row0 +       r1) * K_ + c1;
    const __bf16* a10 = A + (size_t)(row0 + 128 + r0) * K_ + c0;
    const __bf16* a11 = A + (size_t)(row0 + 128 + r1) * K_ + c1;
    const __bf16* b00 = B + (size_t)(col0 +       r0) * K_ + c0;
    const __bf16* b01 = B + (size_t)(col0 +       r1) * K_ + c1;
    const __bf16* b10 = B + (size_t)(col0 + 128 + r0) * K_ + c0;
    const __bf16* b11 = B + (size_t)(col0 + 128 + r1) * K_ + c1;
    const int la0 = q0 * 8, la1 = q1 * 8;

    auto stageA = [&](int d, int h, int kt) {
        __bf16* dst = smA + (d * 2 + h) * 8192;
        gload_lds16((h ? a10 : a00) + kt * 64, dst + la0);
        gload_lds16((h ? a11 : a01) + kt * 64, dst + la1);
    };
    auto stageB = [&](int d, int h, int kt) {
        __bf16* dst = smB + (d * 2 + h) * 8192;
        gload_lds16((h ? b10 : b00) + kt * 64, dst + la0);
        gload_lds16((h ? b11 : b01) + kt * 64, dst + la1);
    };
    // frag reads (swizzled): row-local 16B slot = (kk*4+lg) ^ (row&7)
    auto rdA = [&](int d, int mh, int m16, int kk) -> bf16x8 {
        const int mrow = wr * 64 + m16 * 16 + lr;
        const int off = (d * 2 + mh) * 8192 + mrow * 64 + (((kk * 4 + lg) ^ (mrow & 7)) * 8);
        return *(const bf16x8*)(smA + off);
    };
    auto rdB = [&](int d, int nh, int n16, int kk) -> bf16x8 {
        const int nrow = wc * 32 + n16 * 16 + lr;
        const int off = (d * 2 + nh) * 8192 + nrow * 64 + (((kk * 4 + lg) ^ (nrow & 7)) * 8);
        return *(const bf16x8*)(smB + off);
    };
    auto MF = [&](bf16x8 a, bf16x8 b, f32x4 c) -> f32x4 {
        return __builtin_amdgcn_mfma_f32_16x16x32_bf16(a, b, c, 0, 0, 0);
    };

    // prologue: K-tile 0 fully + A0,B0 of K-tile 1. Gate leaves newest 4 loads.
    stageA(0, 0, 0); stageB(0, 0, 0);
    stageA(0, 1, 0); stageB(0, 1, 0);
    stageA(1, 0, 1); stageB(1, 0, 1);
    asm volatile("s_waitcnt vmcnt(4)" ::: "memory");
    BAR();

    bf16x8 af[4][2];    // current A-half frags [m16][kk]
    bf16x8 bf0[2][2];   // B-half0 [n16][kk]
    bf16x8 bf1[2][2];   // B-half1

    for (int k = 0; k < NT; ++k) {
        const int d   = k & 1;
        const int kt1 = (k + 1 <= NTm1) ? k + 1 : NTm1;
        const int kt2 = (k + 2 <= NTm1) ? k + 2 : NTm1;

        // ---- phase 0: quadrant (mh=0, nh=0); reads A-h0(8) + B-h0(4)
#pragma unroll
        for (int m = 0; m < 4; ++m)
#pragma unroll
            for (int kk = 0; kk < 2; ++kk) af[m][kk] = rdA(d, 0, m, kk);
#pragma unroll
        for (int n = 0; n < 2; ++n)
#pragma unroll
            for (int kk = 0; kk < 2; ++kk) bf0[n][kk] = rdB(d, 0, n, kk);
        stageA(d ^ 1, 1, kt1);                 // A-h1 of k+1 (other buffer)
        BAR();
        __builtin_amdgcn_s_setprio(1);
#pragma unroll
        for (int kk = 0; kk < 2; ++kk)
#pragma unroll
            for (int m = 0; m < 4; ++m)
#pragma unroll
                for (int n = 0; n < 2; ++n)
                    acc[m][n] = MF(af[m][kk], bf0[n][kk], acc[m][n]);
        __builtin_amdgcn_s_setprio(0);
        BAR();

        // ---- phase 1: (mh=0, nh=1); reads B-h1(4), A held
#pragma unroll
        for (int n = 0; n < 2; ++n)
#pragma unroll
            for (int kk = 0; kk < 2; ++kk) bf1[n][kk] = rdB(d, 1, n, kk);
        stageB(d ^ 1, 1, kt1);                 // B-h1 of k+1 (other buffer)
        BAR();
        __builtin_amdgcn_s_setprio(1);
#pragma unroll
        for (int kk = 0; kk < 2; ++kk)
#pragma unroll
            for (int m = 0; m < 4; ++m)
#pragma unroll
                for (int n = 0; n < 2; ++n)
                    acc[m][2 + n] = MF(af[m][kk], bf1[n][kk], acc[m][2 + n]);
        __builtin_amdgcn_s_setprio(0);
        BAR();

        // ---- phase 2: (mh=1, nh=0); reads A-h1(8), B-h0 held
#pragma unroll
        for (int m = 0; m < 4; ++m)
#pragma unroll
            for (int kk = 0; kk < 2; ++kk) af[m][kk] = rdA(d, 1, m, kk);
        stageA(d, 0, kt2);                     // A-h0 freed after phase 1
        BAR();
        __builtin_amdgcn_s_setprio(1);
#pragma unroll
        for (int kk = 0; kk < 2; ++kk)
#pragma unroll
            for (int m = 0; m < 4; ++m)
#pragma unroll
                for (int n = 0; n < 2; ++n)
                    acc[4 + m][n] = MF(af[m][kk], bf0[n][kk], acc[4 + m][n]);
        __builtin_amdgcn_s_setprio(0);
        BAR();

        // ---- phase 3: (mh=1, nh=1); no LDS reads (A,B held)
        stageB(d, 0, kt2);                     // B-h0 freed after phase 2
        asm volatile("s_waitcnt vmcnt(4)" ::: "memory");  // gate K-tile k+1
        BAR();
        __builtin_amdgcn_s_setprio(1);
#pragma unroll
        for (int kk = 0; kk < 2; ++kk)
#pragma unroll
            for (int m = 0; m < 4; ++m)
#pragma unroll
                for (int n = 0; n < 2; ++n)
                    acc[4 + m][2 + n] = MF(af[m][kk], bf1[n][kk], acc[4 + m][2 + n]);
        __builtin_amdgcn_s_setprio(0);
        BAR();
    }

    asm volatile("s_waitcnt vmcnt(0)" ::: "memory");

    // epilogue: frag C/D layout col=lane&15, row=lg*4+j (m89-verified)
    const float s = scale[0];
#pragma unroll
    for (int nh = 0; nh < 2; ++nh)
#pragma unroll
        for (int n16 = 0; n16 < 2; ++n16) {
            const int gc = col0 + nh * 128 + wc * 32 + n16 * 16 + lr;
            const float bv = bias[gc];
#pragma unroll
            for (int mh = 0; mh < 2; ++mh)
#pragma unroll
                for (int m16 = 0; m16 < 4; ++m16) {
                    const int gr = row0 + mh * 128 + wr * 64 + m16 * 16 + lg * 4;
                    const f32x4 v = acc[mh * 4 + m16][nh * 2 + n16];
#pragma unroll
                    for (int j = 0; j < 4; ++j)
                        C[(size_t)(gr + j) * N_ + gc] = v[j] * s + bv;
                }
        }
}

// ------------------------------- launcher ----------------------------------

extern "C" void kernel_launch(void* const* d_in, const int* in_sizes, int n_in,
                              void* d_out, int out_size, void* d_ws, size_t ws_size,
                              hipStream_t stream) {
    const float* x     = (const float*)d_in[0];
    const int*   qw    = (const int*)d_in[1];
    const float* scale = (const float*)d_in[2];
    const float* bias  = (const float*)d_in[3];
    float*       out   = (float*)d_out;

    __bf16* xb = (__bf16*)d_ws;
    __bf16* wb = (__bf16*)((char*)d_ws + (size_t)M_ * K_ * sizeof(__bf16));

    const int n8x = M_ * K_ / 8;
    const int n8w = N_ * K_ / 8;
    k_cvt_x<<<2048, 256, 0, stream>>>(x, xb, n8x);
    k_cvt_w<<<2048, 256, 0, stream>>>(qw, wb, n8w);

    dim3 grid(N_ / 256, M_ / 256);   // (16, 32) = 512 workgroups
    k_gemm<<<grid, 512, 0, stream>>>(xb, wb, scale, bias, out);
}